// Round 9
// baseline (43.239 us; speedup 1.0000x reference)
//
#include <hip/hip_runtime.h>

// HungarianMatcher batched cost matrix. B=64, Q=900, T=300, C=80.
// cost = 5*cbbox + (2*ccls + 2) - 2*(inter*ca + uni^2)/(uni*ca)
//
// R9: two-kernel split. All one-kernel variants (R2-R8) pinned at 34.7-38us
// because per-block staging (focal table: 3 transcendentals/entry + barrier)
// rivals per-block main-loop work. K1 computes the focal table ONCE,
// transposed to ws as clsT[b][c][q] (18.4MB). K2 = R8's 4qx4t loop with
// class values as one float4 L2 load per (t, q-group) and only box staging.

constexpr int B = 64, Q = 900, T = 300, C = 80;
constexpr float ALPHA = 0.25f;
constexpr float EPSF  = 1e-8f;

// ---- kernel 1: focal + transpose ----
constexpr int K1_QT    = 75;              // q per tile
constexpr int K1_TILES = Q / K1_QT;       // 12
constexpr int K1_BLOCK = 256;

// ---- kernel 2: cost matrix ----
constexpr int QTILE = 20;                 // 45 q-tiles -> grid 2880
constexpr int BLOCK = 256;
constexpr int TG    = T / 4;              // 75
constexpr int QG    = QTILE / 4;          // 5
constexpr int NIT   = QG * TG;            // 375

__device__ __forceinline__ float fast_rcp(float x) {
    return __builtin_amdgcn_rcpf(x);
}

__device__ __forceinline__ float focal2(float x) {
    float pr = fast_rcp(1.0f + __expf(-x));
    float om = 1.0f - pr;
    float pos = ALPHA * om * om * (-__logf(pr + EPSF));
    float neg = (1.0f - ALPHA) * pr * pr * (-__logf(om + EPSF));
    return 2.0f * (pos - neg) + 2.0f;     // pre-scaled: W_CLASS*cls + 2
}

__global__ __launch_bounds__(K1_BLOCK) void focal_transpose_kernel(
    const float* __restrict__ logits,     // [B,Q,C]
    float* __restrict__ clsT)             // [B,C,Q]
{
    __shared__ float sT[C * K1_QT];       // [c][q_local], 24 KB

    const int bid  = blockIdx.x;
    const int b    = bid / K1_TILES;
    const int tile = bid - b * K1_TILES;
    const int q0   = tile * K1_QT;
    const int tid  = threadIdx.x;

    const float* lg = logits + ((size_t)b * Q + q0) * C;   // 6000 contiguous
    for (int i4 = tid; i4 < K1_QT * C / 4; i4 += K1_BLOCK) {
        float4 x4 = *(const float4*)(lg + i4 * 4);
        int q  = i4 / (C / 4);
        int c0 = (i4 - q * (C / 4)) * 4;
        #pragma unroll
        for (int j = 0; j < 4; ++j)
            sT[(c0 + j) * K1_QT + q] = focal2((&x4.x)[j]);
    }
    __syncthreads();

    float* ob = clsT + (size_t)b * C * Q + q0;
    for (int j = tid; j < C * K1_QT; j += K1_BLOCK) {
        int c = j / K1_QT, q = j - c * K1_QT;
        ob[(size_t)c * Q + q] = sT[j];    // coalesced 4B stores (lane = q)
    }
}

__global__ __launch_bounds__(BLOCK) void matcher_cost_kernel(
    const float* __restrict__ pboxes,     // [B,Q,4] cxcywh
    const int*   __restrict__ tlabels,    // [B,T]
    const float* __restrict__ tboxes,     // [B,T,4] cxcywh
    const float* __restrict__ clsT,       // [B,C,Q]
    float* __restrict__ out)              // [B,Q,T]
{
    __shared__ float4 s_t[9][TG];         // cx,cy,w,h,x0,y0,x1,y1,area
    __shared__ int4   s_tl[TG];
    __shared__ float4 s_pA[QTILE];        // cx,cy,w,h
    __shared__ float4 s_pB[QTILE];        // x0,y0,x1,y1

    const int bid = blockIdx.x;
    const int b   = bid / (Q / QTILE);
    const int q0  = (bid % (Q / QTILE)) * QTILE;
    const int tid = threadIdx.x;

    for (int t = tid; t < T; t += BLOCK) {
        float4 bx = *(const float4*)(tboxes + ((size_t)b * T + t) * 4);
        float x0 = bx.x - 0.5f * bx.z, y0 = bx.y - 0.5f * bx.w;
        float x1 = bx.x + 0.5f * bx.z, y1 = bx.y + 0.5f * bx.w;
        ((float*)&s_t[0][0])[t] = bx.x;
        ((float*)&s_t[1][0])[t] = bx.y;
        ((float*)&s_t[2][0])[t] = bx.z;
        ((float*)&s_t[3][0])[t] = bx.w;
        ((float*)&s_t[4][0])[t] = x0;
        ((float*)&s_t[5][0])[t] = y0;
        ((float*)&s_t[6][0])[t] = x1;
        ((float*)&s_t[7][0])[t] = y1;
        ((float*)&s_t[8][0])[t] = bx.z * bx.w;
        ((int*)&s_tl[0])[t]     = tlabels[(size_t)b * T + t];
    }
    if (tid < QTILE) {
        float4 bx = *(const float4*)(pboxes + ((size_t)b * Q + q0 + tid) * 4);
        float x0 = bx.x - 0.5f * bx.z, y0 = bx.y - 0.5f * bx.w;
        float x1 = bx.x + 0.5f * bx.z, y1 = bx.y + 0.5f * bx.w;
        s_pA[tid] = bx;
        s_pB[tid] = make_float4(x0, y0, x1, y1);
    }
    __syncthreads();

    const float* ct = clsT + (size_t)b * C * Q + q0;
    float* outb = out + ((size_t)b * Q + q0) * T;

    for (unsigned it = tid; it < NIT; it += BLOCK) {
        unsigned qg = it / TG;            // 0..4
        unsigned tg = it - qg * TG;       // 0..74

        int4 lab = s_tl[tg];

        // class costs for 4 q's per t: L2-resident float4 loads, issued early
        const float* cb = ct + qg * 4;
        float4 clsq0 = *(const float4*)(cb + (unsigned)lab.x * Q);
        float4 clsq1 = *(const float4*)(cb + (unsigned)lab.y * Q);
        float4 clsq2 = *(const float4*)(cb + (unsigned)lab.z * Q);
        float4 clsq3 = *(const float4*)(cb + (unsigned)lab.w * Q);

        float4 tcx = s_t[0][tg], tcy = s_t[1][tg];
        float4 tw  = s_t[2][tg], th  = s_t[3][tg];
        float4 tx0 = s_t[4][tg], ty0 = s_t[5][tg];
        float4 tx1 = s_t[6][tg], ty1 = s_t[7][tg];
        float4 ta  = s_t[8][tg];

        float* o0 = outb + (size_t)(qg * 4) * T + tg * 4;

        #pragma unroll
        for (int dq = 0; dq < 4; ++dq) {
            const int ql = qg * 4 + dq;
            float4 pA = s_pA[ql];         // broadcast b128
            float4 pB = s_pB[ql];
            float  pa = pA.z * pA.w;

            float4 res;
            #pragma unroll
            for (int k = 0; k < 4; ++k) {
                float tcx_ = (&tcx.x)[k], tcy_ = (&tcy.x)[k];
                float tw_  = (&tw.x)[k],  th_  = (&th.x)[k];
                float tx0_ = (&tx0.x)[k], ty0_ = (&ty0.x)[k];
                float tx1_ = (&tx1.x)[k], ty1_ = (&ty1.x)[k];
                float ta_  = (&ta.x)[k];

                float cbbox = (fabsf(pA.x - tcx_) + fabsf(pA.y - tcy_)) +
                              (fabsf(pA.z - tw_ ) + fabsf(pA.w - th_ ));
                float cls2 = (k == 0) ? (&clsq0.x)[dq] :
                             (k == 1) ? (&clsq1.x)[dq] :
                             (k == 2) ? (&clsq2.x)[dq] : (&clsq3.x)[dq];

                float iw = fmaxf(fminf(pB.z, tx1_) - fmaxf(pB.x, tx0_), 0.0f);
                float ih = fmaxf(fminf(pB.w, ty1_) - fmaxf(pB.y, ty0_), 0.0f);
                float inter = iw * ih;
                float uni   = (pa + ta_) - inter;

                float cw = fmaxf(pB.z, tx1_) - fminf(pB.x, tx0_);   // >= 0
                float ch = fmaxf(pB.w, ty1_) - fminf(pB.y, ty0_);   // >= 0
                float ca = cw * ch;

                float num = fmaf(uni, uni, inter * ca);
                float r   = fast_rcp(uni * ca);
                float c   = fmaf(5.0f, cbbox, cls2);
                c = fmaf(num, -2.0f * r, c);

                if (c != c) c = 1.0f;     // nan_to_num; |finite c| << 1e6

                (&res.x)[k] = c;
            }
            *(float4*)(o0 + (size_t)dq * T) = res;
        }
    }
}

// ---- fallback (R7): single kernel, LDS focal table, used if ws too small ----
constexpr int FQT = 18;
constexpr int FNIT = (FQT / 2) * TG;

__global__ __launch_bounds__(BLOCK) void matcher_cost_fallback(
    const float* __restrict__ logits, const float* __restrict__ pboxes,
    const int* __restrict__ tlabels, const float* __restrict__ tboxes,
    float* __restrict__ out)
{
    __shared__ float4 s_t[9][TG];
    __shared__ int4   s_tl[TG];
    __shared__ float  s_cls[FQT * C];
    __shared__ float4 s_pA[FQT];
    __shared__ float4 s_pB[FQT];

    const int bid = blockIdx.x;
    const int b   = bid / (Q / FQT);
    const int q0  = (bid % (Q / FQT)) * FQT;
    const int tid = threadIdx.x;

    for (int t = tid; t < T; t += BLOCK) {
        float4 bx = *(const float4*)(tboxes + ((size_t)b * T + t) * 4);
        float x0 = bx.x - 0.5f * bx.z, y0 = bx.y - 0.5f * bx.w;
        float x1 = bx.x + 0.5f * bx.z, y1 = bx.y + 0.5f * bx.w;
        ((float*)&s_t[0][0])[t] = bx.x; ((float*)&s_t[1][0])[t] = bx.y;
        ((float*)&s_t[2][0])[t] = bx.z; ((float*)&s_t[3][0])[t] = bx.w;
        ((float*)&s_t[4][0])[t] = x0;   ((float*)&s_t[5][0])[t] = y0;
        ((float*)&s_t[6][0])[t] = x1;   ((float*)&s_t[7][0])[t] = y1;
        ((float*)&s_t[8][0])[t] = bx.z * bx.w;
        ((int*)&s_tl[0])[t]     = tlabels[(size_t)b * T + t];
    }
    if (tid < FQT) {
        float4 bx = *(const float4*)(pboxes + ((size_t)b * Q + q0 + tid) * 4);
        s_pA[tid] = bx;
        s_pB[tid] = make_float4(bx.x - 0.5f * bx.z, bx.y - 0.5f * bx.w,
                                bx.x + 0.5f * bx.z, bx.y + 0.5f * bx.w);
    }
    {
        const float* lg = logits + ((size_t)b * Q + q0) * C;
        for (int i = tid; i < FQT * C; i += BLOCK) s_cls[i] = focal2(lg[i]);
    }
    __syncthreads();

    float* outb = out + ((size_t)b * Q + q0) * T;
    for (unsigned it = tid; it < FNIT; it += BLOCK) {
        unsigned qp = it / TG, tg = it - qp * TG;
        float4 tcx = s_t[0][tg], tcy = s_t[1][tg];
        float4 tw  = s_t[2][tg], th  = s_t[3][tg];
        float4 tx0 = s_t[4][tg], ty0 = s_t[5][tg];
        float4 tx1 = s_t[6][tg], ty1 = s_t[7][tg];
        float4 ta  = s_t[8][tg];
        int4   lab = s_tl[tg];
        #pragma unroll
        for (int dq = 0; dq < 2; ++dq) {
            const int ql = qp * 2 + dq;
            float4 pA = s_pA[ql]; float4 pB = s_pB[ql];
            float  pa = pA.z * pA.w;
            const float* clsrow = s_cls + ql * C;
            float4 res;
            #pragma unroll
            for (int k = 0; k < 4; ++k) {
                float cbbox = (fabsf(pA.x - (&tcx.x)[k]) + fabsf(pA.y - (&tcy.x)[k])) +
                              (fabsf(pA.z - (&tw.x)[k])  + fabsf(pA.w - (&th.x)[k]));
                float cls2 = clsrow[(&lab.x)[k]];
                float iw = fmaxf(fminf(pB.z, (&tx1.x)[k]) - fmaxf(pB.x, (&tx0.x)[k]), 0.0f);
                float ih = fmaxf(fminf(pB.w, (&ty1.x)[k]) - fmaxf(pB.y, (&ty0.x)[k]), 0.0f);
                float inter = iw * ih;
                float uni = (pa + (&ta.x)[k]) - inter;
                float cw = fmaxf(pB.z, (&tx1.x)[k]) - fminf(pB.x, (&tx0.x)[k]);
                float ch = fmaxf(pB.w, (&ty1.x)[k]) - fminf(pB.y, (&ty0.x)[k]);
                float ca = cw * ch;
                float num = fmaf(uni, uni, inter * ca);
                float c = fmaf(5.0f, cbbox, cls2);
                c = fmaf(num, -2.0f * fast_rcp(uni * ca), c);
                if (c != c) c = 1.0f;
                (&res.x)[k] = c;
            }
            *(float4*)(outb + (size_t)ql * T + tg * 4) = res;
        }
    }
}

extern "C" void kernel_launch(void* const* d_in, const int* in_sizes, int n_in,
                              void* d_out, int out_size, void* d_ws, size_t ws_size,
                              hipStream_t stream) {
    const float* logits  = (const float*)d_in[0];
    const float* pboxes  = (const float*)d_in[1];
    const int*   tlabels = (const int*)  d_in[2];
    const float* tboxes  = (const float*)d_in[3];
    float* out = (float*)d_out;

    const size_t clsT_bytes = (size_t)B * C * Q * sizeof(float);  // 18.43 MB
    if (ws_size >= clsT_bytes) {
        float* clsT = (float*)d_ws;
        focal_transpose_kernel<<<dim3(B * K1_TILES), dim3(K1_BLOCK), 0, stream>>>(
            logits, clsT);
        matcher_cost_kernel<<<dim3(B * (Q / QTILE)), dim3(BLOCK), 0, stream>>>(
            pboxes, tlabels, tboxes, clsT, out);
    } else {
        matcher_cost_fallback<<<dim3(B * (Q / FQT)), dim3(BLOCK), 0, stream>>>(
            logits, pboxes, tlabels, tboxes, out);
    }
}